// Round 11
// baseline (58.155 us; speedup 1.0000x reference)
//
#include <hip/hip_runtime.h>

// Problem constants
#define NN 4096
#define CC 64
#define C2 32
#define BB 2

#define NSEG   8          // k-split across blocks (r10: 4 -> 8, single-variable)
#define M_BLK  64         // m-tile per block
#define KBLK   64         // k per LDS tile
#define KB_ITERS (NN / NSEG / KBLK)

// Workspace layout (float offsets)
//   q1,k1,q2,k2 : [B][NN] f32
//   v1,v2       : [B][C2][NN] bf16 (ushort)
//   P           : [2][NSEG][B][C2][NN] f32 partials (NSEG=8 -> 33.5 MB, fits)
#define WS_Q1 0
#define WS_K1 8192
#define WS_Q2 16384
#define WS_K2 24576
#define WS_V1 32768
#define WS_V2 163840
#define WS_P  294912

typedef __attribute__((address_space(1))) const unsigned int GUI;
typedef __attribute__((address_space(3))) unsigned int LUI;
typedef __attribute__((ext_vector_type(8))) short bf16x8;
typedef __attribute__((ext_vector_type(4))) float f32x4;

__device__ __forceinline__ void glds16(const void* g, void* l) {
    __builtin_amdgcn_global_load_lds((GUI*)g, (LUI*)l, 16, 0, 0);
}

__device__ __forceinline__ unsigned short bf16_rne(float f) {
    union { float f; unsigned u; } x; x.f = f;
    unsigned u = x.u + 0x7fff + ((x.u >> 16) & 1);
    return (unsigned short)(u >> 16);
}
__device__ __forceinline__ unsigned pack2(float a, float b) {  // a->lo, b->hi
    return (unsigned)bf16_rne(a) | ((unsigned)bf16_rne(b) << 16);
}
__device__ __forceinline__ float sigm_e2(float x) {   // 1/(1+2^x)
    return __builtin_amdgcn_rcpf(1.0f + __builtin_amdgcn_exp2f(x));
}

// ---------------------------------------------------------------------------
// Stage A: 6 projections (byte-identical to the 53.8us r10 build).
// ---------------------------------------------------------------------------
__global__ __launch_bounds__(256) void proj_kernel(
    const float* __restrict__ x1, const float* __restrict__ x2,
    const float* __restrict__ wq1, const float* __restrict__ bq1,
    const float* __restrict__ wk1, const float* __restrict__ bk1,
    const float* __restrict__ wv1, const float* __restrict__ bv1,
    const float* __restrict__ wq2, const float* __restrict__ bq2,
    const float* __restrict__ wk2, const float* __restrict__ bk2,
    const float* __restrict__ wv2, const float* __restrict__ bv2,
    float* __restrict__ ws)
{
    const int ln = threadIdx.x & 63;
    const int og = threadIdx.x >> 6;
    const int n  = blockIdx.x * 64 + ln;
    const int p  = blockIdx.y;
    const int b  = blockIdx.z;

    const float* x; const float* w; const float* bias;
    int mode; float* dstf; unsigned short* dstv;
    switch (p) {
      case 0: x = x1; w = wq1; bias = bq1; mode = 0; dstf = ws + WS_Q1; dstv = 0; break;
      case 1: x = x1; w = wk1; bias = bk1; mode = 0; dstf = ws + WS_K1; dstv = 0; break;
      case 2: x = x1; w = wv1; bias = bv1; mode = 2; dstf = 0; dstv = (unsigned short*)(ws + WS_V1); break;
      case 3: x = x2; w = wq2; bias = bq2; mode = 1; dstf = ws + WS_Q2; dstv = 0; break;
      case 4: x = x2; w = wk2; bias = bk2; mode = 1; dstf = ws + WS_K2; dstv = 0; break;
      default:x = x2; w = wv2; bias = bv2; mode = 2; dstf = 0; dstv = (unsigned short*)(ws + WS_V2); break;
    }

    __shared__ float red[4][C2][64];

    float acc[C2];
    #pragma unroll
    for (int o = 0; o < C2; ++o) acc[o] = 0.0f;

    const float* xb = x + ((size_t)b * CC + og * 16) * NN + n;
    #pragma unroll
    for (int ci = 0; ci < 16; ++ci) {
        const float xv = xb[(size_t)ci * NN];
        #pragma unroll
        for (int o = 0; o < C2; ++o)
            acc[o] += w[o * CC + og * 16 + ci] * xv;
    }
    #pragma unroll
    for (int o = 0; o < C2; ++o) red[og][o][ln] = acc[o];
    __syncthreads();

    float f[8];
    #pragma unroll
    for (int j = 0; j < 8; ++j) {
        const int o = og * 8 + j;
        f[j] = red[0][o][ln] + red[1][o][ln] + red[2][o][ln] + red[3][o][ln]
             + bias[o];
    }

    if (mode == 2) {
        #pragma unroll
        for (int j = 0; j < 8; ++j)
            dstv[((size_t)b * C2 + og * 8 + j) * NN + n] = bf16_rne(f[j]);
    } else {
        float r;
        if (mode == 0) {
            r = f[0];
            #pragma unroll
            for (int j = 1; j < 8; ++j) r = fmaxf(r, f[j]);
        } else {
            r = 0.0f;
            #pragma unroll
            for (int j = 0; j < 8; ++j) r += f[j];
        }
        __syncthreads();
        red[og][0][ln] = r;
        __syncthreads();
        if (og == 0) {
            const float a0 = red[0][0][ln], a1 = red[1][0][ln];
            const float a2 = red[2][0][ln], a3 = red[3][0][ln];
            const float rr = (mode == 0)
                ? fmaxf(fmaxf(a0, a1), fmaxf(a2, a3))
                : (a0 + a1 + a2 + a3) * (1.0f / C2);
            dstf[(size_t)b * NN + n] = rr;
        }
    }
}

// ---------------------------------------------------------------------------
// Stage B (MFMA): byte-identical core to the 53.8us r10 build; only NSEG
// (grid/k-range) changed. 2048 blocks = 8 blocks/CU.
// ---------------------------------------------------------------------------
__global__ __launch_bounds__(256) void attn_mfma(
    const float* __restrict__ q1, const float* __restrict__ k1,
    const float* __restrict__ q2, const float* __restrict__ k2,
    const unsigned short* __restrict__ v1, const unsigned short* __restrict__ v2,
    float* __restrict__ pout)
{
    __shared__ unsigned short vtile[C2 * KBLK];     // 4 KB
    __shared__ unsigned short stile[M_BLK * KBLK];  // 8 KB

    const int tid = threadIdx.x;
    const int wv  = tid >> 6;
    const int ln  = tid & 63;

    const int seg    = blockIdx.y;
    const int z      = blockIdx.z;
    const int branch = z & 1;
    const int b      = z >> 1;
    const int m0     = blockIdx.x * M_BLK;
    const int kstart = seg * (NN / NSEG);

    const float* q; const float* kv; const unsigned short* vbf; float sl2e;
    if (branch == 0) { q = q1; kv = k2; vbf = v1; sl2e =  1.44269504089f; }
    else             { q = q2; kv = k1; vbf = v2; sl2e = -1.44269504089f; }

    const float qs = q[(size_t)b * NN + m0 + ln] * sl2e;

    f32x4 acc[4];
    #pragma unroll
    for (int mt = 0; mt < 4; ++mt) acc[mt] = (f32x4){0.f, 0.f, 0.f, 0.f};

    const int vc = tid >> 3;
    const int vs = tid & 7;
    const unsigned short* vsrc0 = vbf + (size_t)(b * C2 + vc) * NN
                                + ((vs ^ (vc & 7)) << 3);

    for (int kb = 0; kb < KB_ITERS; ++kb) {
        const int k0 = kstart + kb * KBLK;

        glds16(vsrc0 + k0, (char*)vtile + tid * 16);

        const float* kvp = kv + (size_t)b * NN + k0 + (wv << 4);
        const float4 ka = *(const float4*)(kvp);
        const float4 kb4 = *(const float4*)(kvp + 4);
        const float4 kc = *(const float4*)(kvp + 8);
        const float4 kd = *(const float4*)(kvp + 12);

        float s[16];
        s[0]  = sigm_e2(qs * ka.x);  s[1]  = sigm_e2(qs * ka.y);
        s[2]  = sigm_e2(qs * ka.z);  s[3]  = sigm_e2(qs * ka.w);
        s[4]  = sigm_e2(qs * kb4.x); s[5]  = sigm_e2(qs * kb4.y);
        s[6]  = sigm_e2(qs * kb4.z); s[7]  = sigm_e2(qs * kb4.w);
        s[8]  = sigm_e2(qs * kc.x);  s[9]  = sigm_e2(qs * kc.y);
        s[10] = sigm_e2(qs * kc.z);  s[11] = sigm_e2(qs * kc.w);
        s[12] = sigm_e2(qs * kd.x);  s[13] = sigm_e2(qs * kd.y);
        s[14] = sigm_e2(qs * kd.z);  s[15] = sigm_e2(qs * kd.w);

        uint4 w0, w1;
        w0.x = pack2(s[0],  s[1]);  w0.y = pack2(s[2],  s[3]);
        w0.z = pack2(s[4],  s[5]);  w0.w = pack2(s[6],  s[7]);
        w1.x = pack2(s[8],  s[9]);  w1.y = pack2(s[10], s[11]);
        w1.z = pack2(s[12], s[13]); w1.w = pack2(s[14], s[15]);

        char* srow = (char*)stile + ln * 128;
        *(uint4*)(srow + ((((wv << 1) | 0) ^ (ln & 7)) << 4)) = w0;
        *(uint4*)(srow + ((((wv << 1) | 1) ^ (ln & 7)) << 4)) = w1;

        asm volatile("s_waitcnt vmcnt(0)" ::: "memory");
        __syncthreads();

        const int ct  = wv & 1;
        const int ks  = wv >> 1;
        const int col = (ks << 2) + (ln >> 4);
        const int ac  = ct * 16 + (ln & 15);
        const bf16x8 af = *(const bf16x8*)((const char*)vtile
                          + ac * 128 + ((col ^ (ac & 7)) << 4));
        #pragma unroll
        for (int mt = 0; mt < 4; ++mt) {
            const int bm = mt * 16 + (ln & 15);
            const bf16x8 bfr = *(const bf16x8*)((const char*)stile
                               + bm * 128 + ((col ^ (bm & 7)) << 4));
            acc[mt] = __builtin_amdgcn_mfma_f32_16x16x32_bf16(af, bfr, acc[mt], 0, 0, 0);
        }
        __syncthreads();
    }

    // cross-wave k-half reduction (stile reused as f32 scratch)
    float* red = (float*)stile;
    if (wv >= 2) {
        #pragma unroll
        for (int mt = 0; mt < 4; ++mt)
            *(f32x4*)&red[((wv - 2) * 4 + mt) * 256 + ln * 4] = acc[mt];
    }
    __syncthreads();
    if (wv < 2) {
        const size_t obase = (((size_t)(branch * NSEG + seg) * BB + b) * C2) * NN;
        #pragma unroll
        for (int mt = 0; mt < 4; ++mt) {
            const f32x4 o = *(const f32x4*)&red[(wv * 4 + mt) * 256 + ln * 4];
            acc[mt].x += o.x; acc[mt].y += o.y; acc[mt].z += o.z; acc[mt].w += o.w;
            #pragma unroll
            for (int j = 0; j < 4; ++j) {
                const int c = wv * 16 + (ln >> 4) * 4 + j;
                const int m = m0 + mt * 16 + (ln & 15);
                pout[obase + (size_t)c * NN + m] = acc[mt][j];
            }
        }
    }
}

// ---------------------------------------------------------------------------
// Stage C: fused segment-reduce + output conv + gamma + residual.
// seg loop unroll 1 (max 32 loads in flight). Grid 512 blocks = 2/CU.
// ---------------------------------------------------------------------------
__global__ __launch_bounds__(256) void conv_kernel(
    const float* __restrict__ x1, const float* __restrict__ x2,
    const float* __restrict__ wc1, const float* __restrict__ bc1,
    const float* __restrict__ wc2, const float* __restrict__ bc2,
    const float* __restrict__ g1,  const float* __restrict__ g2,
    const float* __restrict__ p,   float* __restrict__ out)
{
    const int m      = blockIdx.x * 256 + threadIdx.x;
    const int co0    = blockIdx.y * 8;
    const int b      = blockIdx.z >> 1;
    const int branch = blockIdx.z & 1;

    const float* w; const float* bias; const float* x; float gamma; float* o;
    if (branch == 0) { w = wc2; bias = bc2; x = x1; gamma = g1[0]; o = out; }
    else             { w = wc1; bias = bc1; x = x2; gamma = g2[0]; o = out + (size_t)BB * CC * NN; }

    float s[C2];
    #pragma unroll
    for (int c = 0; c < C2; ++c) s[c] = 0.0f;

    #pragma unroll 1
    for (int seg = 0; seg < NSEG; ++seg) {
        const float* sb = p + (((size_t)(branch * NSEG + seg) * BB + b) * C2) * NN + m;
        #pragma unroll
        for (int c = 0; c < C2; ++c)
            s[c] += sb[(size_t)c * NN];
    }

    #pragma unroll
    for (int co = co0; co < co0 + 8; ++co) {
        float a = bias[co];
        #pragma unroll
        for (int c = 0; c < C2; ++c)
            a += w[co * C2 + c] * s[c];
        const size_t idx = ((size_t)b * CC + co) * NN + m;
        o[idx] = x[idx] + gamma * a;
    }
}

extern "C" void kernel_launch(void* const* d_in, const int* in_sizes, int n_in,
                              void* d_out, int out_size, void* d_ws, size_t ws_size,
                              hipStream_t stream)
{
    const float* x1  = (const float*)d_in[0];
    const float* x2  = (const float*)d_in[1];
    const float* wq1 = (const float*)d_in[2];
    const float* bq1 = (const float*)d_in[3];
    const float* wk1 = (const float*)d_in[4];
    const float* bk1 = (const float*)d_in[5];
    const float* wv1 = (const float*)d_in[6];
    const float* bv1 = (const float*)d_in[7];
    const float* wc1 = (const float*)d_in[8];
    const float* bc1 = (const float*)d_in[9];
    const float* wq2 = (const float*)d_in[10];
    const float* bq2 = (const float*)d_in[11];
    const float* wk2 = (const float*)d_in[12];
    const float* bk2 = (const float*)d_in[13];
    const float* wv2 = (const float*)d_in[14];
    const float* bv2 = (const float*)d_in[15];
    const float* wc2 = (const float*)d_in[16];
    const float* bc2 = (const float*)d_in[17];
    const float* g1  = (const float*)d_in[18];
    const float* g2  = (const float*)d_in[19];

    float* ws  = (float*)d_ws;
    float* out = (float*)d_out;

    proj_kernel<<<dim3(NN / 64, 6, BB), 256, 0, stream>>>(
        x1, x2, wq1, bq1, wk1, bk1, wv1, bv1,
        wq2, bq2, wk2, bk2, wv2, bv2, ws);

    const float* q1 = ws + WS_Q1; const float* k1 = ws + WS_K1;
    const float* q2 = ws + WS_Q2; const float* k2 = ws + WS_K2;
    const unsigned short* v1 = (const unsigned short*)(ws + WS_V1);
    const unsigned short* v2 = (const unsigned short*)(ws + WS_V2);
    float* pp = ws + WS_P;

    attn_mfma<<<dim3(NN / M_BLK, NSEG, BB * 2), 256, 0, stream>>>(
        q1, k1, q2, k2, v1, v2, pp);

    conv_kernel<<<dim3(NN / 256, 8, BB * 2), 256, 0, stream>>>(
        x1, x2, wc1, bc1, wc2, bc2, g1, g2, pp, out);
}

// Round 12
// 52.450 us; speedup vs baseline: 1.1088x; 1.1088x over previous
//
#include <hip/hip_runtime.h>
#include <hip/hip_bf16.h>

// Problem constants
#define NN 4096
#define CC 64
#define C2 32
#define BB 2

#define NSEG   4          // k-split (r11's 8 regressed: per-block fixed cost dominates)
#define M_BLK  64         // m-tile per block
#define KBLK   64         // k per LDS tile
#define KB_ITERS (NN / NSEG / KBLK)

// Workspace layout (float offsets)
//   q1,k1,q2,k2 : [B][NN] f32
//   v1,v2       : [B][C2][NN] bf16 (ushort)
//   P           : [2][NSEG][B][C2][NN] f32 partials
#define WS_Q1 0
#define WS_K1 8192
#define WS_Q2 16384
#define WS_K2 24576
#define WS_V1 32768
#define WS_V2 163840
#define WS_P  294912

typedef __attribute__((address_space(1))) const unsigned int GUI;
typedef __attribute__((address_space(3))) unsigned int LUI;
typedef __attribute__((ext_vector_type(8))) short bf16x8;
typedef __attribute__((ext_vector_type(4))) float f32x4;

__device__ __forceinline__ void glds16(const void* g, void* l) {
    __builtin_amdgcn_global_load_lds((GUI*)g, (LUI*)l, 16, 0, 0);
}

__device__ __forceinline__ unsigned short bf16_rne(float f) {
    union { float f; unsigned u; } x; x.f = f;
    unsigned u = x.u + 0x7fff + ((x.u >> 16) & 1);
    return (unsigned short)(u >> 16);
}
// HIP-API packed f32->bf16 RNE: .x -> low half, .y -> high half (defined
// by hip_bf16.h memory layout; no asm operand-order guessing -- r8 lesson).
__device__ __forceinline__ unsigned pack2(float a, float b) {
    __hip_bfloat162 h = __float22bfloat162_rn(make_float2(a, b));
    unsigned r; __builtin_memcpy(&r, &h, 4); return r;
}
__device__ __forceinline__ float sigm_e2(float x) {   // 1/(1+2^x)
    return __builtin_amdgcn_rcpf(1.0f + __builtin_amdgcn_exp2f(x));
}

// ---------------------------------------------------------------------------
// Stage A: 6 projections (byte-identical to the 53.8us r10 build).
// ---------------------------------------------------------------------------
__global__ __launch_bounds__(256) void proj_kernel(
    const float* __restrict__ x1, const float* __restrict__ x2,
    const float* __restrict__ wq1, const float* __restrict__ bq1,
    const float* __restrict__ wk1, const float* __restrict__ bk1,
    const float* __restrict__ wv1, const float* __restrict__ bv1,
    const float* __restrict__ wq2, const float* __restrict__ bq2,
    const float* __restrict__ wk2, const float* __restrict__ bk2,
    const float* __restrict__ wv2, const float* __restrict__ bv2,
    float* __restrict__ ws)
{
    const int ln = threadIdx.x & 63;
    const int og = threadIdx.x >> 6;
    const int n  = blockIdx.x * 64 + ln;
    const int p  = blockIdx.y;
    const int b  = blockIdx.z;

    const float* x; const float* w; const float* bias;
    int mode; float* dstf; unsigned short* dstv;
    switch (p) {
      case 0: x = x1; w = wq1; bias = bq1; mode = 0; dstf = ws + WS_Q1; dstv = 0; break;
      case 1: x = x1; w = wk1; bias = bk1; mode = 0; dstf = ws + WS_K1; dstv = 0; break;
      case 2: x = x1; w = wv1; bias = bv1; mode = 2; dstf = 0; dstv = (unsigned short*)(ws + WS_V1); break;
      case 3: x = x2; w = wq2; bias = bq2; mode = 1; dstf = ws + WS_Q2; dstv = 0; break;
      case 4: x = x2; w = wk2; bias = bk2; mode = 1; dstf = ws + WS_K2; dstv = 0; break;
      default:x = x2; w = wv2; bias = bv2; mode = 2; dstf = 0; dstv = (unsigned short*)(ws + WS_V2); break;
    }

    __shared__ float red[4][C2][64];

    float acc[C2];
    #pragma unroll
    for (int o = 0; o < C2; ++o) acc[o] = 0.0f;

    const float* xb = x + ((size_t)b * CC + og * 16) * NN + n;
    #pragma unroll
    for (int ci = 0; ci < 16; ++ci) {
        const float xv = xb[(size_t)ci * NN];
        #pragma unroll
        for (int o = 0; o < C2; ++o)
            acc[o] += w[o * CC + og * 16 + ci] * xv;
    }
    #pragma unroll
    for (int o = 0; o < C2; ++o) red[og][o][ln] = acc[o];
    __syncthreads();

    float f[8];
    #pragma unroll
    for (int j = 0; j < 8; ++j) {
        const int o = og * 8 + j;
        f[j] = red[0][o][ln] + red[1][o][ln] + red[2][o][ln] + red[3][o][ln]
             + bias[o];
    }

    if (mode == 2) {
        #pragma unroll
        for (int j = 0; j < 8; ++j)
            dstv[((size_t)b * C2 + og * 8 + j) * NN + n] = bf16_rne(f[j]);
    } else {
        float r;
        if (mode == 0) {
            r = f[0];
            #pragma unroll
            for (int j = 1; j < 8; ++j) r = fmaxf(r, f[j]);
        } else {
            r = 0.0f;
            #pragma unroll
            for (int j = 0; j < 8; ++j) r += f[j];
        }
        __syncthreads();
        red[og][0][ln] = r;
        __syncthreads();
        if (og == 0) {
            const float a0 = red[0][0][ln], a1 = red[1][0][ln];
            const float a2 = red[2][0][ln], a3 = red[3][0][ln];
            const float rr = (mode == 0)
                ? fmaxf(fmaxf(a0, a1), fmaxf(a2, a3))
                : (a0 + a1 + a2 + a3) * (1.0f / C2);
            dstf[(size_t)b * NN + n] = rr;
        }
    }
}

// ---------------------------------------------------------------------------
// Stage B (MFMA): r10's 53.8us core (single-buffer, 2 barriers, NSEG=4);
// only pack2 changed (HW packed cvt via HIP intrinsic).
// ---------------------------------------------------------------------------
__global__ __launch_bounds__(256) void attn_mfma(
    const float* __restrict__ q1, const float* __restrict__ k1,
    const float* __restrict__ q2, const float* __restrict__ k2,
    const unsigned short* __restrict__ v1, const unsigned short* __restrict__ v2,
    float* __restrict__ pout)
{
    __shared__ unsigned short vtile[C2 * KBLK];     // 4 KB
    __shared__ unsigned short stile[M_BLK * KBLK];  // 8 KB

    const int tid = threadIdx.x;
    const int wv  = tid >> 6;
    const int ln  = tid & 63;

    const int seg    = blockIdx.y;
    const int z      = blockIdx.z;
    const int branch = z & 1;
    const int b      = z >> 1;
    const int m0     = blockIdx.x * M_BLK;
    const int kstart = seg * (NN / NSEG);

    const float* q; const float* kv; const unsigned short* vbf; float sl2e;
    if (branch == 0) { q = q1; kv = k2; vbf = v1; sl2e =  1.44269504089f; }
    else             { q = q2; kv = k1; vbf = v2; sl2e = -1.44269504089f; }

    const float qs = q[(size_t)b * NN + m0 + ln] * sl2e;

    f32x4 acc[4];
    #pragma unroll
    for (int mt = 0; mt < 4; ++mt) acc[mt] = (f32x4){0.f, 0.f, 0.f, 0.f};

    const int vc = tid >> 3;
    const int vs = tid & 7;
    const unsigned short* vsrc0 = vbf + (size_t)(b * C2 + vc) * NN
                                + ((vs ^ (vc & 7)) << 3);

    for (int kb = 0; kb < KB_ITERS; ++kb) {
        const int k0 = kstart + kb * KBLK;

        glds16(vsrc0 + k0, (char*)vtile + tid * 16);

        const float* kvp = kv + (size_t)b * NN + k0 + (wv << 4);
        const float4 ka = *(const float4*)(kvp);
        const float4 kb4 = *(const float4*)(kvp + 4);
        const float4 kc = *(const float4*)(kvp + 8);
        const float4 kd = *(const float4*)(kvp + 12);

        float s[16];
        s[0]  = sigm_e2(qs * ka.x);  s[1]  = sigm_e2(qs * ka.y);
        s[2]  = sigm_e2(qs * ka.z);  s[3]  = sigm_e2(qs * ka.w);
        s[4]  = sigm_e2(qs * kb4.x); s[5]  = sigm_e2(qs * kb4.y);
        s[6]  = sigm_e2(qs * kb4.z); s[7]  = sigm_e2(qs * kb4.w);
        s[8]  = sigm_e2(qs * kc.x);  s[9]  = sigm_e2(qs * kc.y);
        s[10] = sigm_e2(qs * kc.z);  s[11] = sigm_e2(qs * kc.w);
        s[12] = sigm_e2(qs * kd.x);  s[13] = sigm_e2(qs * kd.y);
        s[14] = sigm_e2(qs * kd.z);  s[15] = sigm_e2(qs * kd.w);

        uint4 w0, w1;
        w0.x = pack2(s[0],  s[1]);  w0.y = pack2(s[2],  s[3]);
        w0.z = pack2(s[4],  s[5]);  w0.w = pack2(s[6],  s[7]);
        w1.x = pack2(s[8],  s[9]);  w1.y = pack2(s[10], s[11]);
        w1.z = pack2(s[12], s[13]); w1.w = pack2(s[14], s[15]);

        char* srow = (char*)stile + ln * 128;
        *(uint4*)(srow + ((((wv << 1) | 0) ^ (ln & 7)) << 4)) = w0;
        *(uint4*)(srow + ((((wv << 1) | 1) ^ (ln & 7)) << 4)) = w1;

        asm volatile("s_waitcnt vmcnt(0)" ::: "memory");
        __syncthreads();

        const int ct  = wv & 1;
        const int ks  = wv >> 1;
        const int col = (ks << 2) + (ln >> 4);
        const int ac  = ct * 16 + (ln & 15);
        const bf16x8 af = *(const bf16x8*)((const char*)vtile
                          + ac * 128 + ((col ^ (ac & 7)) << 4));
        #pragma unroll
        for (int mt = 0; mt < 4; ++mt) {
            const int bm = mt * 16 + (ln & 15);
            const bf16x8 bfr = *(const bf16x8*)((const char*)stile
                               + bm * 128 + ((col ^ (bm & 7)) << 4));
            acc[mt] = __builtin_amdgcn_mfma_f32_16x16x32_bf16(af, bfr, acc[mt], 0, 0, 0);
        }
        __syncthreads();
    }

    // cross-wave k-half reduction (stile reused as f32 scratch)
    float* red = (float*)stile;
    if (wv >= 2) {
        #pragma unroll
        for (int mt = 0; mt < 4; ++mt)
            *(f32x4*)&red[((wv - 2) * 4 + mt) * 256 + ln * 4] = acc[mt];
    }
    __syncthreads();
    if (wv < 2) {
        const size_t obase = (((size_t)(branch * NSEG + seg) * BB + b) * C2) * NN;
        #pragma unroll
        for (int mt = 0; mt < 4; ++mt) {
            const f32x4 o = *(const f32x4*)&red[(wv * 4 + mt) * 256 + ln * 4];
            acc[mt].x += o.x; acc[mt].y += o.y; acc[mt].z += o.z; acc[mt].w += o.w;
            #pragma unroll
            for (int j = 0; j < 4; ++j) {
                const int c = wv * 16 + (ln >> 4) * 4 + j;
                const int m = m0 + mt * 16 + (ln & 15);
                pout[obase + (size_t)c * NN + m] = acc[mt][j];
            }
        }
    }
}

// ---------------------------------------------------------------------------
// Stage C: fused segment-reduce + output conv + gamma + residual.
// seg loop unroll 1 (max 32 loads in flight). Grid 512 blocks = 2/CU.
// ---------------------------------------------------------------------------
__global__ __launch_bounds__(256) void conv_kernel(
    const float* __restrict__ x1, const float* __restrict__ x2,
    const float* __restrict__ wc1, const float* __restrict__ bc1,
    const float* __restrict__ wc2, const float* __restrict__ bc2,
    const float* __restrict__ g1,  const float* __restrict__ g2,
    const float* __restrict__ p,   float* __restrict__ out)
{
    const int m      = blockIdx.x * 256 + threadIdx.x;
    const int co0    = blockIdx.y * 8;
    const int b      = blockIdx.z >> 1;
    const int branch = blockIdx.z & 1;

    const float* w; const float* bias; const float* x; float gamma; float* o;
    if (branch == 0) { w = wc2; bias = bc2; x = x1; gamma = g1[0]; o = out; }
    else             { w = wc1; bias = bc1; x = x2; gamma = g2[0]; o = out + (size_t)BB * CC * NN; }

    float s[C2];
    #pragma unroll
    for (int c = 0; c < C2; ++c) s[c] = 0.0f;

    #pragma unroll 1
    for (int seg = 0; seg < NSEG; ++seg) {
        const float* sb = p + (((size_t)(branch * NSEG + seg) * BB + b) * C2) * NN + m;
        #pragma unroll
        for (int c = 0; c < C2; ++c)
            s[c] += sb[(size_t)c * NN];
    }

    #pragma unroll
    for (int co = co0; co < co0 + 8; ++co) {
        float a = bias[co];
        #pragma unroll
        for (int c = 0; c < C2; ++c)
            a += w[co * C2 + c] * s[c];
        const size_t idx = ((size_t)b * CC + co) * NN + m;
        o[idx] = x[idx] + gamma * a;
    }
}

extern "C" void kernel_launch(void* const* d_in, const int* in_sizes, int n_in,
                              void* d_out, int out_size, void* d_ws, size_t ws_size,
                              hipStream_t stream)
{
    const float* x1  = (const float*)d_in[0];
    const float* x2  = (const float*)d_in[1];
    const float* wq1 = (const float*)d_in[2];
    const float* bq1 = (const float*)d_in[3];
    const float* wk1 = (const float*)d_in[4];
    const float* bk1 = (const float*)d_in[5];
    const float* wv1 = (const float*)d_in[6];
    const float* bv1 = (const float*)d_in[7];
    const float* wc1 = (const float*)d_in[8];
    const float* bc1 = (const float*)d_in[9];
    const float* wq2 = (const float*)d_in[10];
    const float* bq2 = (const float*)d_in[11];
    const float* wk2 = (const float*)d_in[12];
    const float* bk2 = (const float*)d_in[13];
    const float* wv2 = (const float*)d_in[14];
    const float* bv2 = (const float*)d_in[15];
    const float* wc2 = (const float*)d_in[16];
    const float* bc2 = (const float*)d_in[17];
    const float* g1  = (const float*)d_in[18];
    const float* g2  = (const float*)d_in[19];

    float* ws  = (float*)d_ws;
    float* out = (float*)d_out;

    proj_kernel<<<dim3(NN / 64, 6, BB), 256, 0, stream>>>(
        x1, x2, wq1, bq1, wk1, bk1, wv1, bv1,
        wq2, bq2, wk2, bk2, wv2, bv2, ws);

    const float* q1 = ws + WS_Q1; const float* k1 = ws + WS_K1;
    const float* q2 = ws + WS_Q2; const float* k2 = ws + WS_K2;
    const unsigned short* v1 = (const unsigned short*)(ws + WS_V1);
    const unsigned short* v2 = (const unsigned short*)(ws + WS_V2);
    float* pp = ws + WS_P;

    attn_mfma<<<dim3(NN / M_BLK, NSEG, BB * 2), 256, 0, stream>>>(
        q1, k1, q2, k2, v1, v2, pp);

    conv_kernel<<<dim3(NN / 256, 8, BB * 2), 256, 0, stream>>>(
        x1, x2, wc1, bc1, wc2, bc2, g1, g2, pp, out);
}

// Round 13
// 51.133 us; speedup vs baseline: 1.1373x; 1.0258x over previous
//
#include <hip/hip_runtime.h>
#include <hip/hip_bf16.h>

// Problem constants
#define NN 4096
#define CC 64
#define C2 32
#define BB 2

#define NSEG   4          // k-split (8 regressed in r11: per-block fixed cost)
#define M_BLK  64         // m-tile per block
#define KBLK   64         // k per LDS tile
#define KB_ITERS (NN / NSEG / KBLK)

// Workspace layout (float offsets)
#define WS_Q1 0
#define WS_K1 8192
#define WS_Q2 16384
#define WS_K2 24576
#define WS_V1 32768
#define WS_V2 163840
#define WS_P  294912

typedef __attribute__((address_space(1))) const unsigned int GUI;
typedef __attribute__((address_space(3))) unsigned int LUI;
typedef __attribute__((ext_vector_type(8))) short bf16x8;
typedef __attribute__((ext_vector_type(4))) float f32x4;

__device__ __forceinline__ void glds16(const void* g, void* l) {
    __builtin_amdgcn_global_load_lds((GUI*)g, (LUI*)l, 16, 0, 0);
}

__device__ __forceinline__ unsigned short bf16_rne(float f) {
    union { float f; unsigned u; } x; x.f = f;
    unsigned u = x.u + 0x7fff + ((x.u >> 16) & 1);
    return (unsigned short)(u >> 16);
}
// HIP-API packed f32->bf16 RNE (r12-proven)
__device__ __forceinline__ unsigned pack2(float a, float b) {
    __hip_bfloat162 h = __float22bfloat162_rn(make_float2(a, b));
    unsigned r; __builtin_memcpy(&r, &h, 4); return r;
}
__device__ __forceinline__ float sigm_e2(float x) {   // 1/(1+2^x)
    return __builtin_amdgcn_rcpf(1.0f + __builtin_amdgcn_exp2f(x));
}

// ---------------------------------------------------------------------------
// Stage A: 6 projections (byte-identical to r12).
// ---------------------------------------------------------------------------
__global__ __launch_bounds__(256) void proj_kernel(
    const float* __restrict__ x1, const float* __restrict__ x2,
    const float* __restrict__ wq1, const float* __restrict__ bq1,
    const float* __restrict__ wk1, const float* __restrict__ bk1,
    const float* __restrict__ wv1, const float* __restrict__ bv1,
    const float* __restrict__ wq2, const float* __restrict__ bq2,
    const float* __restrict__ wk2, const float* __restrict__ bk2,
    const float* __restrict__ wv2, const float* __restrict__ bv2,
    float* __restrict__ ws)
{
    const int ln = threadIdx.x & 63;
    const int og = threadIdx.x >> 6;
    const int n  = blockIdx.x * 64 + ln;
    const int p  = blockIdx.y;
    const int b  = blockIdx.z;

    const float* x; const float* w; const float* bias;
    int mode; float* dstf; unsigned short* dstv;
    switch (p) {
      case 0: x = x1; w = wq1; bias = bq1; mode = 0; dstf = ws + WS_Q1; dstv = 0; break;
      case 1: x = x1; w = wk1; bias = bk1; mode = 0; dstf = ws + WS_K1; dstv = 0; break;
      case 2: x = x1; w = wv1; bias = bv1; mode = 2; dstf = 0; dstv = (unsigned short*)(ws + WS_V1); break;
      case 3: x = x2; w = wq2; bias = bq2; mode = 1; dstf = ws + WS_Q2; dstv = 0; break;
      case 4: x = x2; w = wk2; bias = bk2; mode = 1; dstf = ws + WS_K2; dstv = 0; break;
      default:x = x2; w = wv2; bias = bv2; mode = 2; dstf = 0; dstv = (unsigned short*)(ws + WS_V2); break;
    }

    __shared__ float red[4][C2][64];

    float acc[C2];
    #pragma unroll
    for (int o = 0; o < C2; ++o) acc[o] = 0.0f;

    const float* xb = x + ((size_t)b * CC + og * 16) * NN + n;
    #pragma unroll
    for (int ci = 0; ci < 16; ++ci) {
        const float xv = xb[(size_t)ci * NN];
        #pragma unroll
        for (int o = 0; o < C2; ++o)
            acc[o] += w[o * CC + og * 16 + ci] * xv;
    }
    #pragma unroll
    for (int o = 0; o < C2; ++o) red[og][o][ln] = acc[o];
    __syncthreads();

    float f[8];
    #pragma unroll
    for (int j = 0; j < 8; ++j) {
        const int o = og * 8 + j;
        f[j] = red[0][o][ln] + red[1][o][ln] + red[2][o][ln] + red[3][o][ln]
             + bias[o];
    }

    if (mode == 2) {
        #pragma unroll
        for (int j = 0; j < 8; ++j)
            dstv[((size_t)b * C2 + og * 8 + j) * NN + n] = bf16_rne(f[j]);
    } else {
        float r;
        if (mode == 0) {
            r = f[0];
            #pragma unroll
            for (int j = 1; j < 8; ++j) r = fmaxf(r, f[j]);
        } else {
            r = 0.0f;
            #pragma unroll
            for (int j = 0; j < 8; ++j) r += f[j];
        }
        __syncthreads();
        red[og][0][ln] = r;
        __syncthreads();
        if (og == 0) {
            const float a0 = red[0][0][ln], a1 = red[1][0][ln];
            const float a2 = red[2][0][ln], a3 = red[3][0][ln];
            const float rr = (mode == 0)
                ? fmaxf(fmaxf(a0, a1), fmaxf(a2, a3))
                : (a0 + a1 + a2 + a3) * (1.0f / C2);
            dstf[(size_t)b * NN + n] = rr;
        }
    }
}

// ---------------------------------------------------------------------------
// Stage B (MFMA, double-buffered, ONE barrier per iter, k-loads issued
// BEFORE the MFMA phase so L2 latency hides under MFMA+ds_read).
// Race audit per inter-barrier region: reads {V[cur],S[cur]}, writes
// {V[cur^1] via DMA, S[cur^1] via ds_write} -- disjoint. vmcnt(0) drains
// DMA + k-loads before the barrier; __syncthreads covers lgkm.
// ---------------------------------------------------------------------------
__global__ __launch_bounds__(256) void attn_mfma(
    const float* __restrict__ q1, const float* __restrict__ k1,
    const float* __restrict__ q2, const float* __restrict__ k2,
    const unsigned short* __restrict__ v1, const unsigned short* __restrict__ v2,
    float* __restrict__ pout)
{
    __shared__ unsigned short vtile[2][C2 * KBLK];     // 2 x 4 KB
    __shared__ unsigned short stile[2][M_BLK * KBLK];  // 2 x 8 KB

    const int tid = threadIdx.x;
    const int wv  = tid >> 6;
    const int ln  = tid & 63;

    const int seg    = blockIdx.y;
    const int z      = blockIdx.z;
    const int branch = z & 1;
    const int b      = z >> 1;
    const int m0     = blockIdx.x * M_BLK;
    const int kstart = seg * (NN / NSEG);

    const float* q; const float* kv; const unsigned short* vbf; float sl2e;
    if (branch == 0) { q = q1; kv = k2; vbf = v1; sl2e =  1.44269504089f; }
    else             { q = q2; kv = k1; vbf = v2; sl2e = -1.44269504089f; }

    const float qs = q[(size_t)b * NN + m0 + ln] * sl2e;
    const float* kvb = kv + (size_t)b * NN;

    f32x4 acc[4];
    #pragma unroll
    for (int mt = 0; mt < 4; ++mt) acc[mt] = (f32x4){0.f, 0.f, 0.f, 0.f};

    const int vc = tid >> 3;
    const int vs = tid & 7;
    const unsigned short* vsrc0 = vbf + (size_t)(b * C2 + vc) * NN
                                + ((vs ^ (vc & 7)) << 3);

    // sigmoid + pack + swizzled ds_write of one S-tile column-block
    auto sigPackWrite = [&](int buf, float4 ka, float4 kb4, float4 kc, float4 kd) {
        float s[16];
        s[0]  = sigm_e2(qs * ka.x);  s[1]  = sigm_e2(qs * ka.y);
        s[2]  = sigm_e2(qs * ka.z);  s[3]  = sigm_e2(qs * ka.w);
        s[4]  = sigm_e2(qs * kb4.x); s[5]  = sigm_e2(qs * kb4.y);
        s[6]  = sigm_e2(qs * kb4.z); s[7]  = sigm_e2(qs * kb4.w);
        s[8]  = sigm_e2(qs * kc.x);  s[9]  = sigm_e2(qs * kc.y);
        s[10] = sigm_e2(qs * kc.z);  s[11] = sigm_e2(qs * kc.w);
        s[12] = sigm_e2(qs * kd.x);  s[13] = sigm_e2(qs * kd.y);
        s[14] = sigm_e2(qs * kd.z);  s[15] = sigm_e2(qs * kd.w);

        uint4 w0, w1;
        w0.x = pack2(s[0],  s[1]);  w0.y = pack2(s[2],  s[3]);
        w0.z = pack2(s[4],  s[5]);  w0.w = pack2(s[6],  s[7]);
        w1.x = pack2(s[8],  s[9]);  w1.y = pack2(s[10], s[11]);
        w1.z = pack2(s[12], s[13]); w1.w = pack2(s[14], s[15]);

        char* srow = (char*)stile[buf] + ln * 128;
        *(uint4*)(srow + ((((wv << 1) | 0) ^ (ln & 7)) << 4)) = w0;
        *(uint4*)(srow + ((((wv << 1) | 1) ^ (ln & 7)) << 4)) = w1;
    };

    // prologue: stage V[0] + compute S[0]
    glds16(vsrc0 + kstart, (char*)vtile[0] + tid * 16);
    {
        const float* kvp = kvb + kstart + (wv << 4);
        sigPackWrite(0, *(const float4*)(kvp),     *(const float4*)(kvp + 4),
                        *(const float4*)(kvp + 8), *(const float4*)(kvp + 12));
    }
    asm volatile("s_waitcnt vmcnt(0)" ::: "memory");
    __syncthreads();

    const int ct  = wv & 1;
    const int ks  = wv >> 1;
    const int col = (ks << 2) + (ln >> 4);
    const int ac  = ct * 16 + (ln & 15);

    for (int kb = 0; kb < KB_ITERS; ++kb) {
        const int cur = kb & 1;
        const bool more = (kb + 1 < KB_ITERS);

        float4 ka, kb4, kc, kd;
        if (more) {
            // issue next V DMA + next k-loads FIRST (latency hides under MFMA)
            glds16(vsrc0 + kstart + (kb + 1) * KBLK,
                   (char*)vtile[cur ^ 1] + tid * 16);
            const float* kvp = kvb + kstart + (kb + 1) * KBLK + (wv << 4);
            ka  = *(const float4*)(kvp);
            kb4 = *(const float4*)(kvp + 4);
            kc  = *(const float4*)(kvp + 8);
            kd  = *(const float4*)(kvp + 12);
        }

        const bf16x8 af = *(const bf16x8*)((const char*)vtile[cur]
                          + ac * 128 + ((col ^ (ac & 7)) << 4));
        #pragma unroll
        for (int mt = 0; mt < 4; ++mt) {
            const int bm = mt * 16 + (ln & 15);
            const bf16x8 bfr = *(const bf16x8*)((const char*)stile[cur]
                               + bm * 128 + ((col ^ (bm & 7)) << 4));
            acc[mt] = __builtin_amdgcn_mfma_f32_16x16x32_bf16(af, bfr, acc[mt], 0, 0, 0);
        }

        if (more) sigPackWrite(cur ^ 1, ka, kb4, kc, kd);

        asm volatile("s_waitcnt vmcnt(0)" ::: "memory");
        __syncthreads();
    }

    // cross-wave k-half reduction (stile reused as f32 scratch, 8 KB needed)
    float* red = (float*)stile;
    if (wv >= 2) {
        #pragma unroll
        for (int mt = 0; mt < 4; ++mt)
            *(f32x4*)&red[((wv - 2) * 4 + mt) * 256 + ln * 4] = acc[mt];
    }
    __syncthreads();
    if (wv < 2) {
        const size_t obase = (((size_t)(branch * NSEG + seg) * BB + b) * C2) * NN;
        #pragma unroll
        for (int mt = 0; mt < 4; ++mt) {
            const f32x4 o = *(const f32x4*)&red[(wv * 4 + mt) * 256 + ln * 4];
            acc[mt].x += o.x; acc[mt].y += o.y; acc[mt].z += o.z; acc[mt].w += o.w;
            #pragma unroll
            for (int j = 0; j < 4; ++j) {
                const int c = wv * 16 + (ln >> 4) * 4 + j;
                const int m = m0 + mt * 16 + (ln & 15);
                pout[obase + (size_t)c * NN + m] = acc[mt][j];
            }
        }
    }
}

// ---------------------------------------------------------------------------
// Stage C: fused segment-reduce + conv + gamma + residual (byte-identical
// to r12: seg loop unroll 1, max 32 loads in flight).
// ---------------------------------------------------------------------------
__global__ __launch_bounds__(256) void conv_kernel(
    const float* __restrict__ x1, const float* __restrict__ x2,
    const float* __restrict__ wc1, const float* __restrict__ bc1,
    const float* __restrict__ wc2, const float* __restrict__ bc2,
    const float* __restrict__ g1,  const float* __restrict__ g2,
    const float* __restrict__ p,   float* __restrict__ out)
{
    const int m      = blockIdx.x * 256 + threadIdx.x;
    const int co0    = blockIdx.y * 8;
    const int b      = blockIdx.z >> 1;
    const int branch = blockIdx.z & 1;

    const float* w; const float* bias; const float* x; float gamma; float* o;
    if (branch == 0) { w = wc2; bias = bc2; x = x1; gamma = g1[0]; o = out; }
    else             { w = wc1; bias = bc1; x = x2; gamma = g2[0]; o = out + (size_t)BB * CC * NN; }

    float s[C2];
    #pragma unroll
    for (int c = 0; c < C2; ++c) s[c] = 0.0f;

    #pragma unroll 1
    for (int seg = 0; seg < NSEG; ++seg) {
        const float* sb = p + (((size_t)(branch * NSEG + seg) * BB + b) * C2) * NN + m;
        #pragma unroll
        for (int c = 0; c < C2; ++c)
            s[c] += sb[(size_t)c * NN];
    }

    #pragma unroll
    for (int co = co0; co < co0 + 8; ++co) {
        float a = bias[co];
        #pragma unroll
        for (int c = 0; c < C2; ++c)
            a += w[co * C2 + c] * s[c];
        const size_t idx = ((size_t)b * CC + co) * NN + m;
        o[idx] = x[idx] + gamma * a;
    }
}

extern "C" void kernel_launch(void* const* d_in, const int* in_sizes, int n_in,
                              void* d_out, int out_size, void* d_ws, size_t ws_size,
                              hipStream_t stream)
{
    const float* x1  = (const float*)d_in[0];
    const float* x2  = (const float*)d_in[1];
    const float* wq1 = (const float*)d_in[2];
    const float* bq1 = (const float*)d_in[3];
    const float* wk1 = (const float*)d_in[4];
    const float* bk1 = (const float*)d_in[5];
    const float* wv1 = (const float*)d_in[6];
    const float* bv1 = (const float*)d_in[7];
    const float* wc1 = (const float*)d_in[8];
    const float* bc1 = (const float*)d_in[9];
    const float* wq2 = (const float*)d_in[10];
    const float* bq2 = (const float*)d_in[11];
    const float* wk2 = (const float*)d_in[12];
    const float* bk2 = (const float*)d_in[13];
    const float* wv2 = (const float*)d_in[14];
    const float* bv2 = (const float*)d_in[15];
    const float* wc2 = (const float*)d_in[16];
    const float* bc2 = (const float*)d_in[17];
    const float* g1  = (const float*)d_in[18];
    const float* g2  = (const float*)d_in[19];

    float* ws  = (float*)d_ws;
    float* out = (float*)d_out;

    proj_kernel<<<dim3(NN / 64, 6, BB), 256, 0, stream>>>(
        x1, x2, wq1, bq1, wk1, bk1, wv1, bv1,
        wq2, bq2, wk2, bk2, wv2, bv2, ws);

    const float* q1 = ws + WS_Q1; const float* k1 = ws + WS_K1;
    const float* q2 = ws + WS_Q2; const float* k2 = ws + WS_K2;
    const unsigned short* v1 = (const unsigned short*)(ws + WS_V1);
    const unsigned short* v2 = (const unsigned short*)(ws + WS_V2);
    float* pp = ws + WS_P;

    attn_mfma<<<dim3(NN / M_BLK, NSEG, BB * 2), 256, 0, stream>>>(
        q1, k1, q2, k2, v1, v2, pp);

    conv_kernel<<<dim3(NN / 256, 8, BB * 2), 256, 0, stream>>>(
        x1, x2, wc1, bc1, wc2, bc2, g1, g2, pp, out);
}

// Round 14
// 49.833 us; speedup vs baseline: 1.1670x; 1.0261x over previous
//
#include <hip/hip_runtime.h>
#include <hip/hip_bf16.h>

// Problem constants
#define NN 4096
#define CC 64
#define C2 32
#define BB 2

#define NSEG   4          // k-split (8 regressed in r11)
#define M_BLK  32         // m-tile per block (r14: 64 -> 32 for 8 blocks/CU)
#define KBLK   64         // k per LDS tile
#define KB_ITERS (NN / NSEG / KBLK)

// Workspace layout (float offsets)
#define WS_Q1 0
#define WS_K1 8192
#define WS_Q2 16384
#define WS_K2 24576
#define WS_V1 32768
#define WS_V2 163840
#define WS_P  294912

typedef __attribute__((address_space(1))) const unsigned int GUI;
typedef __attribute__((address_space(3))) unsigned int LUI;
typedef __attribute__((ext_vector_type(8))) short bf16x8;
typedef __attribute__((ext_vector_type(4))) float f32x4;

__device__ __forceinline__ void glds16(const void* g, void* l) {
    __builtin_amdgcn_global_load_lds((GUI*)g, (LUI*)l, 16, 0, 0);
}

__device__ __forceinline__ unsigned short bf16_rne(float f) {
    union { float f; unsigned u; } x; x.f = f;
    unsigned u = x.u + 0x7fff + ((x.u >> 16) & 1);
    return (unsigned short)(u >> 16);
}
// HIP-API packed f32->bf16 RNE (r12-proven)
__device__ __forceinline__ unsigned pack2(float a, float b) {
    __hip_bfloat162 h = __float22bfloat162_rn(make_float2(a, b));
    unsigned r; __builtin_memcpy(&r, &h, 4); return r;
}
__device__ __forceinline__ float sigm_e2(float x) {   // 1/(1+2^x)
    return __builtin_amdgcn_rcpf(1.0f + __builtin_amdgcn_exp2f(x));
}

// ---------------------------------------------------------------------------
// Stage A: 6 projections (byte-identical to r12/r13).
// ---------------------------------------------------------------------------
__global__ __launch_bounds__(256) void proj_kernel(
    const float* __restrict__ x1, const float* __restrict__ x2,
    const float* __restrict__ wq1, const float* __restrict__ bq1,
    const float* __restrict__ wk1, const float* __restrict__ bk1,
    const float* __restrict__ wv1, const float* __restrict__ bv1,
    const float* __restrict__ wq2, const float* __restrict__ bq2,
    const float* __restrict__ wk2, const float* __restrict__ bk2,
    const float* __restrict__ wv2, const float* __restrict__ bv2,
    float* __restrict__ ws)
{
    const int ln = threadIdx.x & 63;
    const int og = threadIdx.x >> 6;
    const int n  = blockIdx.x * 64 + ln;
    const int p  = blockIdx.y;
    const int b  = blockIdx.z;

    const float* x; const float* w; const float* bias;
    int mode; float* dstf; unsigned short* dstv;
    switch (p) {
      case 0: x = x1; w = wq1; bias = bq1; mode = 0; dstf = ws + WS_Q1; dstv = 0; break;
      case 1: x = x1; w = wk1; bias = bk1; mode = 0; dstf = ws + WS_K1; dstv = 0; break;
      case 2: x = x1; w = wv1; bias = bv1; mode = 2; dstf = 0; dstv = (unsigned short*)(ws + WS_V1); break;
      case 3: x = x2; w = wq2; bias = bq2; mode = 1; dstf = ws + WS_Q2; dstv = 0; break;
      case 4: x = x2; w = wk2; bias = bk2; mode = 1; dstf = ws + WS_K2; dstv = 0; break;
      default:x = x2; w = wv2; bias = bv2; mode = 2; dstf = 0; dstv = (unsigned short*)(ws + WS_V2); break;
    }

    __shared__ float red[4][C2][64];

    float acc[C2];
    #pragma unroll
    for (int o = 0; o < C2; ++o) acc[o] = 0.0f;

    const float* xb = x + ((size_t)b * CC + og * 16) * NN + n;
    #pragma unroll
    for (int ci = 0; ci < 16; ++ci) {
        const float xv = xb[(size_t)ci * NN];
        #pragma unroll
        for (int o = 0; o < C2; ++o)
            acc[o] += w[o * CC + og * 16 + ci] * xv;
    }
    #pragma unroll
    for (int o = 0; o < C2; ++o) red[og][o][ln] = acc[o];
    __syncthreads();

    float f[8];
    #pragma unroll
    for (int j = 0; j < 8; ++j) {
        const int o = og * 8 + j;
        f[j] = red[0][o][ln] + red[1][o][ln] + red[2][o][ln] + red[3][o][ln]
             + bias[o];
    }

    if (mode == 2) {
        #pragma unroll
        for (int j = 0; j < 8; ++j)
            dstv[((size_t)b * C2 + og * 8 + j) * NN + n] = bf16_rne(f[j]);
    } else {
        float r;
        if (mode == 0) {
            r = f[0];
            #pragma unroll
            for (int j = 1; j < 8; ++j) r = fmaxf(r, f[j]);
        } else {
            r = 0.0f;
            #pragma unroll
            for (int j = 0; j < 8; ++j) r += f[j];
        }
        __syncthreads();
        red[og][0][ln] = r;
        __syncthreads();
        if (og == 0) {
            const float a0 = red[0][0][ln], a1 = red[1][0][ln];
            const float a2 = red[2][0][ln], a3 = red[3][0][ln];
            const float rr = (mode == 0)
                ? fmaxf(fmaxf(a0, a1), fmaxf(a2, a3))
                : (a0 + a1 + a2 + a3) * (1.0f / C2);
            dstf[(size_t)b * NN + n] = rr;
        }
    }
}

// ---------------------------------------------------------------------------
// Stage B (MFMA, dbuf, 1 barrier/iter, M_BLK=32): S-tile 32m x 64k; thread
// = (m = tid&31, k-chunk = tid>>5): 8 sigmoids + 1 swizzled uint4 ds_write
// per iter. Waves: (ct = wv&1 c-tile, ks = wv>>1 k-half), 2 MFMA each.
// 2048 blocks = 8 blocks/CU = 8 waves/SIMD (TLP deepened 4 -> 8).
// ---------------------------------------------------------------------------
__global__ __launch_bounds__(256) void attn_mfma(
    const float* __restrict__ q1, const float* __restrict__ k1,
    const float* __restrict__ q2, const float* __restrict__ k2,
    const unsigned short* __restrict__ v1, const unsigned short* __restrict__ v2,
    float* __restrict__ pout)
{
    __shared__ unsigned short vtile[2][C2 * KBLK];     // 2 x 4 KB
    __shared__ unsigned short stile[2][M_BLK * KBLK];  // 2 x 4 KB

    const int tid = threadIdx.x;
    const int wv  = tid >> 6;
    const int ln  = tid & 63;

    const int seg    = blockIdx.y;
    const int z      = blockIdx.z;
    const int branch = z & 1;
    const int b      = z >> 1;
    const int m0     = blockIdx.x * M_BLK;
    const int kstart = seg * (NN / NSEG);

    const float* q; const float* kv; const unsigned short* vbf; float sl2e;
    if (branch == 0) { q = q1; kv = k2; vbf = v1; sl2e =  1.44269504089f; }
    else             { q = q2; kv = k1; vbf = v2; sl2e = -1.44269504089f; }

    const int sm = tid & 31;           // S row (m) this thread computes
    const int sc = tid >> 5;           // k-chunk 0..7 (8 k each)
    const float qs = q[(size_t)b * NN + m0 + sm] * sl2e;
    const float* kvb = kv + (size_t)b * NN;

    f32x4 acc[2];
    #pragma unroll
    for (int mt = 0; mt < 2; ++mt) acc[mt] = (f32x4){0.f, 0.f, 0.f, 0.f};

    const int vc = tid >> 3;           // V c-row 0..31
    const int vs = tid & 7;            // dest slot 0..7
    const unsigned short* vsrc0 = vbf + (size_t)(b * C2 + vc) * NN
                                + ((vs ^ (vc & 7)) << 3);

    // sigmoid + pack + swizzled ds_write of this thread's 8-k chunk
    auto sigPackWrite = [&](int buf, float4 ka, float4 kb4) {
        float s[8];
        s[0] = sigm_e2(qs * ka.x);  s[1] = sigm_e2(qs * ka.y);
        s[2] = sigm_e2(qs * ka.z);  s[3] = sigm_e2(qs * ka.w);
        s[4] = sigm_e2(qs * kb4.x); s[5] = sigm_e2(qs * kb4.y);
        s[6] = sigm_e2(qs * kb4.z); s[7] = sigm_e2(qs * kb4.w);

        uint4 w;
        w.x = pack2(s[0], s[1]); w.y = pack2(s[2], s[3]);
        w.z = pack2(s[4], s[5]); w.w = pack2(s[6], s[7]);

        char* srow = (char*)stile[buf] + sm * 128;
        *(uint4*)(srow + ((sc ^ (sm & 7)) << 4)) = w;
    };

    // prologue: stage V[0] + compute S[0]
    glds16(vsrc0 + kstart, (char*)vtile[0] + tid * 16);
    {
        const float* kvp = kvb + kstart + sc * 8;
        sigPackWrite(0, *(const float4*)(kvp), *(const float4*)(kvp + 4));
    }
    asm volatile("s_waitcnt vmcnt(0)" ::: "memory");
    __syncthreads();

    const int ct  = wv & 1;
    const int ks  = wv >> 1;
    const int col = (ks << 2) + (ln >> 4);   // slot 0..7
    const int ac  = ct * 16 + (ln & 15);     // V row (c)

    for (int kb = 0; kb < KB_ITERS; ++kb) {
        const int cur = kb & 1;
        const bool more = (kb + 1 < KB_ITERS);

        float4 ka, kb4;
        if (more) {
            glds16(vsrc0 + kstart + (kb + 1) * KBLK,
                   (char*)vtile[cur ^ 1] + tid * 16);
            const float* kvp = kvb + kstart + (kb + 1) * KBLK + sc * 8;
            ka  = *(const float4*)(kvp);
            kb4 = *(const float4*)(kvp + 4);
        }

        const bf16x8 af = *(const bf16x8*)((const char*)vtile[cur]
                          + ac * 128 + ((col ^ (ac & 7)) << 4));
        #pragma unroll
        for (int mt = 0; mt < 2; ++mt) {
            const int bm = mt * 16 + (ln & 15);
            const bf16x8 bfr = *(const bf16x8*)((const char*)stile[cur]
                               + bm * 128 + ((col ^ (bm & 7)) << 4));
            acc[mt] = __builtin_amdgcn_mfma_f32_16x16x32_bf16(af, bfr, acc[mt], 0, 0, 0);
        }

        if (more) sigPackWrite(cur ^ 1, ka, kb4);

        asm volatile("s_waitcnt vmcnt(0)" ::: "memory");
        __syncthreads();
    }

    // cross-wave k-half reduction (stile reused as f32 scratch: 4x256 f32 = 4KB)
    float* red = (float*)stile;
    if (wv >= 2) {
        #pragma unroll
        for (int mt = 0; mt < 2; ++mt)
            *(f32x4*)&red[((wv - 2) * 2 + mt) * 256 + ln * 4] = acc[mt];
    }
    __syncthreads();
    if (wv < 2) {
        const size_t obase = (((size_t)(branch * NSEG + seg) * BB + b) * C2) * NN;
        #pragma unroll
        for (int mt = 0; mt < 2; ++mt) {
            const f32x4 o = *(const f32x4*)&red[(wv * 2 + mt) * 256 + ln * 4];
            acc[mt].x += o.x; acc[mt].y += o.y; acc[mt].z += o.z; acc[mt].w += o.w;
            #pragma unroll
            for (int j = 0; j < 4; ++j) {
                const int c = wv * 16 + (ln >> 4) * 4 + j;
                const int m = m0 + mt * 16 + (ln & 15);
                pout[obase + (size_t)c * NN + m] = acc[mt][j];
            }
        }
    }
}

// ---------------------------------------------------------------------------
// Stage C: fused segment-reduce + conv + gamma + residual (byte-identical
// to r12/r13).
// ---------------------------------------------------------------------------
__global__ __launch_bounds__(256) void conv_kernel(
    const float* __restrict__ x1, const float* __restrict__ x2,
    const float* __restrict__ wc1, const float* __restrict__ bc1,
    const float* __restrict__ wc2, const float* __restrict__ bc2,
    const float* __restrict__ g1,  const float* __restrict__ g2,
    const float* __restrict__ p,   float* __restrict__ out)
{
    const int m      = blockIdx.x * 256 + threadIdx.x;
    const int co0    = blockIdx.y * 8;
    const int b      = blockIdx.z >> 1;
    const int branch = blockIdx.z & 1;

    const float* w; const float* bias; const float* x; float gamma; float* o;
    if (branch == 0) { w = wc2; bias = bc2; x = x1; gamma = g1[0]; o = out; }
    else             { w = wc1; bias = bc1; x = x2; gamma = g2[0]; o = out + (size_t)BB * CC * NN; }

    float s[C2];
    #pragma unroll
    for (int c = 0; c < C2; ++c) s[c] = 0.0f;

    #pragma unroll 1
    for (int seg = 0; seg < NSEG; ++seg) {
        const float* sb = p + (((size_t)(branch * NSEG + seg) * BB + b) * C2) * NN + m;
        #pragma unroll
        for (int c = 0; c < C2; ++c)
            s[c] += sb[(size_t)c * NN];
    }

    #pragma unroll
    for (int co = co0; co < co0 + 8; ++co) {
        float a = bias[co];
        #pragma unroll
        for (int c = 0; c < C2; ++c)
            a += w[co * C2 + c] * s[c];
        const size_t idx = ((size_t)b * CC + co) * NN + m;
        o[idx] = x[idx] + gamma * a;
    }
}

extern "C" void kernel_launch(void* const* d_in, const int* in_sizes, int n_in,
                              void* d_out, int out_size, void* d_ws, size_t ws_size,
                              hipStream_t stream)
{
    const float* x1  = (const float*)d_in[0];
    const float* x2  = (const float*)d_in[1];
    const float* wq1 = (const float*)d_in[2];
    const float* bq1 = (const float*)d_in[3];
    const float* wk1 = (const float*)d_in[4];
    const float* bk1 = (const float*)d_in[5];
    const float* wv1 = (const float*)d_in[6];
    const float* bv1 = (const float*)d_in[7];
    const float* wc1 = (const float*)d_in[8];
    const float* bc1 = (const float*)d_in[9];
    const float* wq2 = (const float*)d_in[10];
    const float* bq2 = (const float*)d_in[11];
    const float* wk2 = (const float*)d_in[12];
    const float* bk2 = (const float*)d_in[13];
    const float* wv2 = (const float*)d_in[14];
    const float* bv2 = (const float*)d_in[15];
    const float* wc2 = (const float*)d_in[16];
    const float* bc2 = (const float*)d_in[17];
    const float* g1  = (const float*)d_in[18];
    const float* g2  = (const float*)d_in[19];

    float* ws  = (float*)d_ws;
    float* out = (float*)d_out;

    proj_kernel<<<dim3(NN / 64, 6, BB), 256, 0, stream>>>(
        x1, x2, wq1, bq1, wk1, bk1, wv1, bv1,
        wq2, bq2, wk2, bk2, wv2, bv2, ws);

    const float* q1 = ws + WS_Q1; const float* k1 = ws + WS_K1;
    const float* q2 = ws + WS_Q2; const float* k2 = ws + WS_K2;
    const unsigned short* v1 = (const unsigned short*)(ws + WS_V1);
    const unsigned short* v2 = (const unsigned short*)(ws + WS_V2);
    float* pp = ws + WS_P;

    attn_mfma<<<dim3(NN / M_BLK, NSEG, BB * 2), 256, 0, stream>>>(
        q1, k1, q2, k2, v1, v2, pp);

    conv_kernel<<<dim3(NN / 256, 8, BB * 2), 256, 0, stream>>>(
        x1, x2, wc1, bc1, wc2, bc2, g1, g2, pp, out);
}